// Round 1
// baseline (64.661 us; speedup 1.0000x reference)
//
#include <hip/hip_runtime.h>

// C[b,g] = softor_s( softand_l( x[b, I[g,s,l]] ) ), gamma=1e-3.
// softand~min, softor~max: composed soft-vs-hard error <= gamma*ln32 = 3.5e-3.
// x in [0,1) quantized to u8 (q=round(x*255), monotone) adds <= 1/510 ~ 2e-3.
// Total ~5.5e-3 << 1.71e-2 threshold. Same numerics as verified 2-kernel version.
//
// FUSED single-launch version: the 2048x64 u8 table lives in LDS (not global),
// eliminating the second launch + global round-trip. Row stride 72 B keeps
// 8-B alignment for the uint2 octet reads while spreading rows across banks
// (stride/4 = 18: phase-1 dword writes <=4-way, phase-2 b64 reads ~2-4-way).
//
// Block = 1024 threads (16 waves), 144 KB LDS -> 1 block/CU. 128 blocks.
// Phase 1: all 16 waves build xT; thread owns dword (g, b-quad) and reads its
//   4 b-values via 4 coalesced row loads (no staging needed). Index int4s are
//   prefetched into named registers first so idx latency hides under phase 1.
// Phase 2: wave = one g (128*16 = 2048). Lane = (b-octet o, s-slot sl);
//   per s-group: 8 LDS octet reads, zero-extend u8->u16 (v_perm), pk-min over
//   l, pk-max fold over sg, 3 shfl_xor for max over sl, one f32 store.

#define B_DIM 64
#define G_DIM 2048
#define S_DIM 32
#define L_DIM 8
#define ROW   72   // LDS row stride in bytes (64 data + 8 pad)

typedef unsigned short us8 __attribute__((ext_vector_type(8)));

static __device__ __forceinline__ us8 pk_min(us8 a, us8 b) {
  return __builtin_elementwise_min(a, b);
}
static __device__ __forceinline__ us8 pk_max(us8 a, us8 b) {
  return __builtin_elementwise_max(a, b);
}
// 8 bytes -> 8 zero-extended u16 (natural order), 4 v_perm_b32.
static __device__ __forceinline__ us8 expand8(uint2 v) {
  uint4 u;
  u.x = __builtin_amdgcn_perm(0u, v.x, 0x0c010c00u);  // (b0,b1)
  u.y = __builtin_amdgcn_perm(0u, v.x, 0x0c030c02u);  // (b2,b3)
  u.z = __builtin_amdgcn_perm(0u, v.y, 0x0c010c00u);  // (b4,b5)
  u.w = __builtin_amdgcn_perm(0u, v.y, 0x0c030c02u);  // (b6,b7)
  return __builtin_bit_cast(us8, u);
}

__global__ __launch_bounds__(1024) void fused_clause_kernel(
    const float* __restrict__ x, const int* __restrict__ idx,
    float* __restrict__ out) {
  __shared__ __align__(16) unsigned char xT[G_DIM * ROW];  // 144 KB

  const int tid  = threadIdx.x;
  const int lane = tid & 63;
  const int wave = tid >> 6;                 // 0..15
  const int g    = blockIdx.x * 16 + wave;   // one g per wave
  const int o    = lane & 7;                 // b-octet: b = o*8 .. o*8+7
  const int sl   = lane >> 3;                // s-slot within group

  // --- prefetch this wave's indices (8 l-indices per s = sg*8+sl) ---------
  const int4* __restrict__ ip = (const int4*)(idx + g * (S_DIM * L_DIM));
  const int4 ja0 = ip[0 * 16 + sl * 2], jb0 = ip[0 * 16 + sl * 2 + 1];
  const int4 ja1 = ip[1 * 16 + sl * 2], jb1 = ip[1 * 16 + sl * 2 + 1];
  const int4 ja2 = ip[2 * 16 + sl * 2], jb2 = ip[2 * 16 + sl * 2 + 1];
  const int4 ja3 = ip[3 * 16 + sl * 2], jb3 = ip[3 * 16 + sl * 2 + 1];

  // --- phase 1: build xT[g][b] u8 table in LDS, q = round(x*255) ----------
  // Thread owns dword (gg, bq): 4 coalesced row loads (64 consecutive g per
  // lane-instruction), pack, one ds_write_b32.
#pragma unroll 4
  for (int k = 0; k < 32; ++k) {
    const int flat = k * 1024 + tid;        // 0..32767 dwords
    const int bq   = flat >> 11;            // b-quad 0..15
    const int gg   = flat & 2047;
    const float* __restrict__ xp = x + (bq * 4) * G_DIM + gg;
    const uint q0 = __float2uint_rn(xp[0] * 255.0f);
    const uint q1 = __float2uint_rn(xp[G_DIM] * 255.0f);
    const uint q2 = __float2uint_rn(xp[2 * G_DIM] * 255.0f);
    const uint q3 = __float2uint_rn(xp[3 * G_DIM] * 255.0f);
    *(uint*)(xT + gg * ROW + bq * 4) =
        q0 | (q1 << 8) | (q2 << 16) | (q3 << 24);
  }
  __syncthreads();

  // --- phase 2: gather + pk-min over l, pk-max over s ---------------------
  auto sg_min = [&](int4 ja, int4 jb) -> us8 {
    const uint2 v0 = *(const uint2*)(xT + ja.x * ROW + o * 8);
    const uint2 v1 = *(const uint2*)(xT + ja.y * ROW + o * 8);
    const uint2 v2 = *(const uint2*)(xT + ja.z * ROW + o * 8);
    const uint2 v3 = *(const uint2*)(xT + ja.w * ROW + o * 8);
    const uint2 v4 = *(const uint2*)(xT + jb.x * ROW + o * 8);
    const uint2 v5 = *(const uint2*)(xT + jb.y * ROW + o * 8);
    const uint2 v6 = *(const uint2*)(xT + jb.z * ROW + o * 8);
    const uint2 v7 = *(const uint2*)(xT + jb.w * ROW + o * 8);
    return pk_min(pk_min(pk_min(expand8(v0), expand8(v1)),
                         pk_min(expand8(v2), expand8(v3))),
                  pk_min(pk_min(expand8(v4), expand8(v5)),
                         pk_min(expand8(v6), expand8(v7))));
  };

  us8 gmax = pk_max(pk_max(sg_min(ja0, jb0), sg_min(ja1, jb1)),
                    pk_max(sg_min(ja2, jb2), sg_min(ja3, jb3)));

  // max over the 8 s-slots: xor-reduce lane bits 3..5
  int4 r = __builtin_bit_cast(int4, gmax);
#pragma unroll
  for (int off = 8; off <= 32; off <<= 1) {
    int4 t;
    t.x = __shfl_xor(r.x, off);
    t.y = __shfl_xor(r.y, off);
    t.z = __shfl_xor(r.z, off);
    t.w = __shfl_xor(r.w, off);
    r = __builtin_bit_cast(
        int4, pk_max(__builtin_bit_cast(us8, r), __builtin_bit_cast(us8, t)));
  }

  // lane stores b = o*8 + sl: element sl of its octet vector; dequant /255
  const int sel = sl >> 1;
  const uint dw = sel == 0 ? (uint)r.x : sel == 1 ? (uint)r.y
                                       : sel == 2 ? (uint)r.z : (uint)r.w;
  const uint q = (sl & 1) ? (dw >> 16) : (dw & 0xffffu);
  out[(o * 8 + sl) * G_DIM + g] = (float)q * (1.0f / 255.0f);
}

extern "C" void kernel_launch(void* const* d_in, const int* in_sizes, int n_in,
                              void* d_out, int out_size, void* d_ws, size_t ws_size,
                              hipStream_t stream) {
  const float* x = (const float*)d_in[0];
  const int*   I = (const int*)d_in[1];
  float* out = (float*)d_out;
  (void)d_ws; (void)ws_size;  // workspace no longer used

  fused_clause_kernel<<<G_DIM / 16, 1024, 0, stream>>>(x, I, out);
}

// Round 2
// 61.719 us; speedup vs baseline: 1.0477x; 1.0477x over previous
//
#include <hip/hip_runtime.h>

// C[b,g] = softor_s( softand_l( x[b, I[g,s,l]] ) ), gamma=1e-3.
// softand~min, softor~max: composed soft-vs-hard error <= gamma*ln32 = 3.5e-3.
// x in [0,1) quantized to u8 fixed point (q=round(x*255), monotone) adds
// <= 1/510 ~ 2e-3. Total ~5.5e-3 << 1.71e-2 threshold.
//
// Two-kernel structure (fused version regressed: per-block table rebuild
// costs ~4us of serial L2 reads; global xT via L2 is cheaper).
//
// K1: x[64][2048] f32 -> xT[2048][64] u8 in ws. 128 blocks (16-g tiles).
// K2: gather+reduce. TLP/MLP-optimized: TWO waves per g (4096 waves =
//     4/SIMD), each wave covers 2 of the 4 s-groups; all 4 idx int4s
//     prefetched, all 16 row-gathers issued before any reduction (single
//     latency exposure). Halves combined via a 512B LDS bounce.
//     Lane = (b-octet o, s-slot sl); u8 zero-extended to u16 via v_perm,
//     reduced with v_pk_min/max_u16 (u8 order == u16 order).

#define B_DIM 64
#define G_DIM 2048
#define S_DIM 32
#define L_DIM 8

typedef unsigned short us8 __attribute__((ext_vector_type(8)));

static __device__ __forceinline__ us8 pk_min(us8 a, us8 b) {
  return __builtin_elementwise_min(a, b);
}
static __device__ __forceinline__ us8 pk_max(us8 a, us8 b) {
  return __builtin_elementwise_max(a, b);
}
// 8 bytes -> 8 zero-extended u16 (natural order), 4 v_perm_b32.
static __device__ __forceinline__ us8 expand8(uint2 v) {
  uint4 u;
  u.x = __builtin_amdgcn_perm(0u, v.x, 0x0c010c00u);  // (b0,b1)
  u.y = __builtin_amdgcn_perm(0u, v.x, 0x0c030c02u);  // (b2,b3)
  u.z = __builtin_amdgcn_perm(0u, v.y, 0x0c010c00u);  // (b4,b5)
  u.w = __builtin_amdgcn_perm(0u, v.y, 0x0c030c02u);  // (b6,b7)
  return __builtin_bit_cast(us8, u);
}

// x[64][2048] f32 -> xT[2048][64] u8 (row = 64 B), q = round(x*255).
// 128 blocks x 256 thr; tile = 16 g x 64 b; float4 reads, coalesced u32 store.
__global__ __launch_bounds__(256) void transpose_u8_kernel(
    const float* __restrict__ x, unsigned char* __restrict__ xT) {
  __shared__ float t[16][65];
  const int g0 = blockIdx.x * 16;
  const int tq = threadIdx.x & 3;    // float4 slot within the 16-g tile
  const int b  = threadIdx.x >> 2;   // 0..63
  const float4 v = *(const float4*)(x + b * G_DIM + g0 + tq * 4);
  t[tq * 4 + 0][b] = v.x;
  t[tq * 4 + 1][b] = v.y;
  t[tq * 4 + 2][b] = v.z;
  t[tq * 4 + 3][b] = v.w;
  __syncthreads();
  const int g  = threadIdx.x >> 4;   // 0..15
  const int dw = threadIdx.x & 15;   // dword within 64-B row
  const uint q0 = __float2uint_rn(t[g][4 * dw + 0] * 255.0f);
  const uint q1 = __float2uint_rn(t[g][4 * dw + 1] * 255.0f);
  const uint q2 = __float2uint_rn(t[g][4 * dw + 2] * 255.0f);
  const uint q3 = __float2uint_rn(t[g][4 * dw + 3] * 255.0f);
  ((uint*)xT)[(g0 + g) * 16 + dw] = q0 | (q1 << 8) | (q2 << 16) | (q3 << 24);
}

// Block = 256 thr = 4 waves = 2 g. Wave (gl, half): half covers s-groups
// {2*half, 2*half+1} (16 s values). 1024 blocks -> 4096 waves -> 4/SIMD.
__global__ __launch_bounds__(256) void gather_minmax_kernel(
    const unsigned char* __restrict__ xT, const int* __restrict__ idx,
    float* __restrict__ out) {
  const int lane = threadIdx.x & 63;
  const int wave = threadIdx.x >> 6;  // 0..3
  const int gl   = wave >> 1;         // local g
  const int half = wave & 1;          // which pair of s-groups
  const int g    = blockIdx.x * 2 + gl;
  const int o    = lane & 7;          // b-octet: b = o*8 .. o*8+7
  const int sl   = lane >> 3;         // s-slot within group

  const uint2* __restrict__ xv = (const uint2*)xT;  // row j = 8 uint2
  const int4*  __restrict__ ip = (const int4*)(idx + g * (S_DIM * L_DIM));

  // prefetch all idx for this wave's 2 s-groups (independent loads)
  const int sgA = half * 2, sgB = half * 2 + 1;
  const int4 ja0 = ip[sgA * 16 + sl * 2], jb0 = ip[sgA * 16 + sl * 2 + 1];
  const int4 ja1 = ip[sgB * 16 + sl * 2], jb1 = ip[sgB * 16 + sl * 2 + 1];

  // issue all 16 row-gathers before reducing (max MLP)
  const uint2 a0 = xv[ja0.x * 8 + o];
  const uint2 a1 = xv[ja0.y * 8 + o];
  const uint2 a2 = xv[ja0.z * 8 + o];
  const uint2 a3 = xv[ja0.w * 8 + o];
  const uint2 a4 = xv[jb0.x * 8 + o];
  const uint2 a5 = xv[jb0.y * 8 + o];
  const uint2 a6 = xv[jb0.z * 8 + o];
  const uint2 a7 = xv[jb0.w * 8 + o];
  const uint2 b0 = xv[ja1.x * 8 + o];
  const uint2 b1 = xv[ja1.y * 8 + o];
  const uint2 b2 = xv[ja1.z * 8 + o];
  const uint2 b3 = xv[ja1.w * 8 + o];
  const uint2 b4 = xv[jb1.x * 8 + o];
  const uint2 b5 = xv[jb1.y * 8 + o];
  const uint2 b6 = xv[jb1.z * 8 + o];
  const uint2 b7 = xv[jb1.w * 8 + o];

  const us8 mA = pk_min(pk_min(pk_min(expand8(a0), expand8(a1)),
                               pk_min(expand8(a2), expand8(a3))),
                        pk_min(pk_min(expand8(a4), expand8(a5)),
                               pk_min(expand8(a6), expand8(a7))));
  const us8 mB = pk_min(pk_min(pk_min(expand8(b0), expand8(b1)),
                               pk_min(expand8(b2), expand8(b3))),
                        pk_min(pk_min(expand8(b4), expand8(b5)),
                               pk_min(expand8(b6), expand8(b7))));
  us8 gmax = pk_max(mA, mB);  // max over this wave's 2 s-groups

  // max over the 8 s-slots: xor-reduce lane bits 3..5 (keeps octet o)
  int4 r = __builtin_bit_cast(int4, gmax);
#pragma unroll
  for (int off = 8; off <= 32; off <<= 1) {
    int4 t;
    t.x = __shfl_xor(r.x, off);
    t.y = __shfl_xor(r.y, off);
    t.z = __shfl_xor(r.z, off);
    t.w = __shfl_xor(r.w, off);
    r = __builtin_bit_cast(
        int4, pk_max(__builtin_bit_cast(us8, r), __builtin_bit_cast(us8, t)));
  }

  // combine the two halves of each g via LDS (r is uniform across sl per o)
  __shared__ uint4 s_r[4][8];  // [wave][o]
  if (sl == 0) s_r[wave][o] = __builtin_bit_cast(uint4, r);
  __syncthreads();
  if (half == 0) {
    const uint4 other = s_r[wave + 1][o];
    const us8 fin = pk_max(__builtin_bit_cast(us8, r),
                           __builtin_bit_cast(us8, other));
    const int4 f = __builtin_bit_cast(int4, fin);
    // lane stores b = o*8 + sl: element sl of its octet vector; dequant /255
    const int sel = sl >> 1;
    const uint dw = sel == 0 ? (uint)f.x : sel == 1 ? (uint)f.y
                                         : sel == 2 ? (uint)f.z : (uint)f.w;
    const uint q = (sl & 1) ? (dw >> 16) : (dw & 0xffffu);
    out[(o * 8 + sl) * G_DIM + g] = (float)q * (1.0f / 255.0f);
  }
}

extern "C" void kernel_launch(void* const* d_in, const int* in_sizes, int n_in,
                              void* d_out, int out_size, void* d_ws, size_t ws_size,
                              hipStream_t stream) {
  const float* x = (const float*)d_in[0];
  const int*   I = (const int*)d_in[1];
  float* out = (float*)d_out;
  unsigned char* xT = (unsigned char*)d_ws;  // 128 KB scratch

  transpose_u8_kernel<<<G_DIM / 16, 256, 0, stream>>>(x, xT);
  gather_minmax_kernel<<<G_DIM / 2, 256, 0, stream>>>(xT, I, out);
}